// Round 3
// baseline (3522.823 us; speedup 1.0000x reference)
//
#include <hip/hip_runtime.h>
#include <math.h>

// ESN: 512 sequential steps of h = tanh([h | x_t] @ [W_hh|W_ih]^T + b)
// T=512, B=64, I=128, H=1024, K' = 1152.
//
// R7 (from R6 @ 3.13 ms): decentralized per-(WG,row) flag sync.
//  * Each wave owns one batch row: epilogue (lanes 0-7), wave-lockstep drain,
//    then IMMEDIATE per-row flag publish -- no __syncthreads between data
//    drain and flag store. Only 2 syncthreads per step remain.
//  * Consumers poll per-chunk: lane l stages bytes [64l,64l+64) of its row,
//    which depend on exactly one producer (p = l>>1). Flag line per
//    (bgrp,row) is 32 contiguous dwords -> one coalesced 128B poll load per
//    wave per iteration.
//  * Producer's own 32 columns are mirrored into LDS at epilogue time; the 2
//    own-chunk lanes skip poll+reload (own-flag RT off the critical path).
//  * Publish-then-poll: each wave's flag is in flight while peers finish
//    their epilogues (flag RT overlaps remote epilogue time).
//  * Kept from R6: W (18 float4) + bias in VGPRs for all 512 steps,
//    write-through sc0/sc1 data stores (no buffer_wbl2), x_t prefetch.

#define T_STEPS 512
#define BATCH   64
#define HDIM    1024
#define IDIM    128
#define KDIM    1152
#define NWG     256
#define NB      8

typedef float f32x4_t __attribute__((ext_vector_type(4)));

__device__ __forceinline__ unsigned sc_load(const unsigned* p) {
    unsigned v;
    asm volatile("global_load_dword %0, %1, off sc0 sc1\n\ts_waitcnt vmcnt(0)"
                 : "=&v"(v) : "v"(p) : "memory");
    return v;
}

// 64B contiguous bypass load: 4 dwordx4 off one address, single drain
__device__ __forceinline__ void sc_load64(const float* p, float4& a, float4& b,
                                          float4& c, float4& d) {
    asm volatile(
        "global_load_dwordx4 %0, %4, off sc0 sc1\n\t"
        "global_load_dwordx4 %1, %4, off offset:16 sc0 sc1\n\t"
        "global_load_dwordx4 %2, %4, off offset:32 sc0 sc1\n\t"
        "global_load_dwordx4 %3, %4, off offset:48 sc0 sc1\n\t"
        "s_waitcnt vmcnt(0)"
        : "=&v"(a), "=&v"(b), "=&v"(c), "=&v"(d)
        : "v"(p)
        : "memory");
}

// write-through store to the coherence point + drain (wave-lockstep: the
// scalar s_waitcnt drains the whole wave's outstanding stores).
__device__ __forceinline__ void sc_store4(float* p, float4 v) {
    f32x4_t t;
    t.x = v.x; t.y = v.y; t.z = v.z; t.w = v.w;
    asm volatile("global_store_dwordx4 %0, %1, off sc0 sc1\n\ts_waitcnt vmcnt(0)"
                 :: "v"(p), "v"(t) : "memory");
}

__device__ __forceinline__ void flag_store(unsigned* p, unsigned v) {
    asm volatile("global_store_dword %0, %1, off sc0 sc1"
                 :: "v"(p), "v"(v) : "memory");
}

// src[R][C] -> dst[C][R], 64x64 LDS tiles, grid = (C/64)*(R/64), 256 thr
__global__ void transpose_f32(const float* __restrict__ src, float* __restrict__ dst,
                              int R, int C) {
    __shared__ float tile[64][65];
    const int tcol = threadIdx.x & 63;
    const int trow = threadIdx.x >> 6;
    const int nbx = C >> 6;
    const int bx = blockIdx.x % nbx;
    const int by = blockIdx.x / nbx;
    const int c0 = bx << 6, r0 = by << 6;
    for (int i = trow; i < 64; i += 4)
        tile[i][tcol] = src[(size_t)(r0 + i) * C + c0 + tcol];
    __syncthreads();
    for (int i = trow; i < 64; i += 4)
        dst[(size_t)(c0 + i) * R + r0 + tcol] = tile[tcol][i];
}

__global__ __launch_bounds__(512) void esn_persistent(
    const float* __restrict__ x,     // [512][64][128]
    const float* __restrict__ h0,    // [64][1024]
    const float* __restrict__ WT,    // [1152][1024]
    const float* __restrict__ bias,  // [1024]
    float* __restrict__ out,         // [512][64][1024]
    float* __restrict__ hfin,        // [64][1024]
    unsigned* flags)                 // [8 bgrp][8 row][32 jblk] dwords
{
    const int tid  = threadIdx.x;
    const int wg   = blockIdx.x;
    const int wave = tid >> 6;                       // 0..7 = owned batch row
    const int lane = tid & 63;
    const int jq   = lane & 7;                       // 4 j each -> 32 j
    const int ksub = lane >> 3;                      // 0..7 k-interleave
    const int jblk = ((wg & 7) << 2) | ((wg >> 3) & 3);  // XCD owns 4 jblks
    const int bgrp = wg >> 5;                            // 0..7
    const int b0   = bgrp << 3;
    const int j0   = (jblk << 5) + (jq << 2);
    const int krec = wave << 7;                      // recurrent k base (128/wave)
    const int kx   = HDIM + (wave << 4) + (ksub << 1);  // x-part rows (2 each)

    __shared__ float  ht[NB][KDIM];                  // 36.9 KB row-major
    __shared__ float4 red[8 * 8 * 9];                // [w][jq] stride 9, +b pad

    // ---- hoist all 18 W float4 loads for ALL 512 steps (72 VGPRs) ----
    float4 Wv[18];
    {
        const float* wp = WT + (size_t)krec * HDIM + j0;
        #pragma unroll
        for (int i = 0; i < 4; ++i) {
            const int kk = ((i << 3) + ksub) << 2;      // 0..124 step 4
            const float* wk = wp + (size_t)kk * HDIM;
            Wv[i * 4 + 0] = *(const float4*)(wk);
            Wv[i * 4 + 1] = *(const float4*)(wk + HDIM);
            Wv[i * 4 + 2] = *(const float4*)(wk + 2 * HDIM);
            Wv[i * 4 + 3] = *(const float4*)(wk + 3 * HDIM);
        }
        const float* wkx = WT + (size_t)kx * HDIM + j0;
        Wv[16] = *(const float4*)(wkx);
        Wv[17] = *(const float4*)(wkx + HDIM);
    }

    // ---- epilogue constants: lanes 0-7 of EVERY wave handle row b0+wave ----
    float4 b4 = make_float4(0.f, 0.f, 0.f, 0.f);
    int jj = 0;
    if (lane < 8) {
        jj = (jblk << 5) + (lane << 2);
        b4 = *(const float4*)(bias + jj);
    }

    // own chunk: lane stages bytes [64*lane, 64*lane+64) of its row; the two
    // lanes covering bytes [128*jblk, 128*jblk+128) use the LDS mirror.
    const bool own = ((lane >> 1) == jblk);

    // per-row flag line: 32 contiguous dwords per (bgrp,row)
    unsigned* fl_base = flags + (((bgrp << 3) + wave) << 5);
    const unsigned* fl_poll = fl_base + (lane >> 1);

    // ---- prefetch x row for t=0 (plain cached load, x is read-only) ----
    float4 xv = make_float4(0.f, 0.f, 0.f, 0.f);
    if (lane < 32)
        xv = *(const float4*)(x + (size_t)(b0 + wave) * IDIM + (lane << 2));

    for (int t = 0; t < T_STEPS; ++t) {
        // ---- stage [h_{t-1} | x_t] row (b0+wave) into LDS ----
        if (lane < 32)
            *(float4*)&ht[wave][HDIM + (lane << 2)] = xv;
        if (t == 0) {
            float4 a, b, c, d;
            const float* p = h0 + (size_t)(b0 + wave) * HDIM + (lane << 4);
            sc_load64(p, a, b, c, d);
            *(float4*)&ht[wave][(lane << 4) + 0]  = a;
            *(float4*)&ht[wave][(lane << 4) + 4]  = b;
            *(float4*)&ht[wave][(lane << 4) + 8]  = c;
            *(float4*)&ht[wave][(lane << 4) + 12] = d;
        } else if (!own) {
            while (sc_load(fl_poll) < (unsigned)t) {}
            float4 a, b, c, d;
            const float* p = out + ((size_t)(t - 1) * BATCH + b0 + wave) * HDIM
                             + (lane << 4);
            sc_load64(p, a, b, c, d);
            *(float4*)&ht[wave][(lane << 4) + 0]  = a;
            *(float4*)&ht[wave][(lane << 4) + 4]  = b;
            *(float4*)&ht[wave][(lane << 4) + 8]  = c;
            *(float4*)&ht[wave][(lane << 4) + 12] = d;
        }
        __syncthreads();                               // S3: ht complete

        // prefetch next x row; latency hides under the FMA phase
        if (t + 1 < T_STEPS && lane < 32)
            xv = *(const float4*)(x + ((size_t)(t + 1) * BATCH + b0 + wave) * IDIM
                                  + (lane << 2));

        // ---- FMA: acc[b] over this thread's k (W in registers) ----
        float4 acc[NB];
        #pragma unroll
        for (int bb = 0; bb < NB; ++bb) acc[bb] = make_float4(0.f, 0.f, 0.f, 0.f);

        #pragma unroll
        for (int i = 0; i < 4; ++i) {
            const int kk = krec + ((((i << 3) + ksub)) << 2);
            const float4 w0 = Wv[i * 4 + 0], w1 = Wv[i * 4 + 1];
            const float4 w2 = Wv[i * 4 + 2], w3 = Wv[i * 4 + 3];
            #pragma unroll
            for (int bb = 0; bb < NB; ++bb) {
                float4 h4 = *(const float4*)&ht[bb][kk];
                acc[bb].x = fmaf(w0.x, h4.x, acc[bb].x);
                acc[bb].y = fmaf(w0.y, h4.x, acc[bb].y);
                acc[bb].z = fmaf(w0.z, h4.x, acc[bb].z);
                acc[bb].w = fmaf(w0.w, h4.x, acc[bb].w);
                acc[bb].x = fmaf(w1.x, h4.y, acc[bb].x);
                acc[bb].y = fmaf(w1.y, h4.y, acc[bb].y);
                acc[bb].z = fmaf(w1.z, h4.y, acc[bb].z);
                acc[bb].w = fmaf(w1.w, h4.y, acc[bb].w);
                acc[bb].x = fmaf(w2.x, h4.z, acc[bb].x);
                acc[bb].y = fmaf(w2.y, h4.z, acc[bb].y);
                acc[bb].z = fmaf(w2.z, h4.z, acc[bb].z);
                acc[bb].w = fmaf(w2.w, h4.z, acc[bb].w);
                acc[bb].x = fmaf(w3.x, h4.w, acc[bb].x);
                acc[bb].y = fmaf(w3.y, h4.w, acc[bb].y);
                acc[bb].z = fmaf(w3.z, h4.w, acc[bb].z);
                acc[bb].w = fmaf(w3.w, h4.w, acc[bb].w);
            }
        }
        // x tail: 2 k per thread
        #pragma unroll
        for (int bb = 0; bb < NB; ++bb) {
            float2 hx = *(const float2*)&ht[bb][kx];
            acc[bb].x = fmaf(Wv[16].x, hx.x, acc[bb].x);
            acc[bb].y = fmaf(Wv[16].y, hx.x, acc[bb].y);
            acc[bb].z = fmaf(Wv[16].z, hx.x, acc[bb].z);
            acc[bb].w = fmaf(Wv[16].w, hx.x, acc[bb].w);
            acc[bb].x = fmaf(Wv[17].x, hx.y, acc[bb].x);
            acc[bb].y = fmaf(Wv[17].y, hx.y, acc[bb].y);
            acc[bb].z = fmaf(Wv[17].z, hx.y, acc[bb].z);
            acc[bb].w = fmaf(Wv[17].w, hx.y, acc[bb].w);
        }

        // ---- reduce over ksub (lane bits 3,4,5) ----
        #pragma unroll
        for (int bb = 0; bb < NB; ++bb) {
            acc[bb].x += __shfl_xor(acc[bb].x, 8);
            acc[bb].y += __shfl_xor(acc[bb].y, 8);
            acc[bb].z += __shfl_xor(acc[bb].z, 8);
            acc[bb].w += __shfl_xor(acc[bb].w, 8);
            acc[bb].x += __shfl_xor(acc[bb].x, 16);
            acc[bb].y += __shfl_xor(acc[bb].y, 16);
            acc[bb].z += __shfl_xor(acc[bb].z, 16);
            acc[bb].w += __shfl_xor(acc[bb].w, 16);
            acc[bb].x += __shfl_xor(acc[bb].x, 32);
            acc[bb].y += __shfl_xor(acc[bb].y, 32);
            acc[bb].z += __shfl_xor(acc[bb].z, 32);
            acc[bb].w += __shfl_xor(acc[bb].w, 32);
        }
        if (ksub == 0) {
            #pragma unroll
            for (int bb = 0; bb < NB; ++bb)
                red[((wave << 3) + jq) * 9 + bb] = acc[bb];
        }
        __syncthreads();                               // S1: red complete

        // ---- per-wave epilogue for row b0+wave: lanes 0-7 ----
        if (lane < 8) {
            float4 s = make_float4(0.f, 0.f, 0.f, 0.f);
            #pragma unroll
            for (int w = 0; w < 8; ++w) {
                float4 r = red[((w << 3) + lane) * 9 + wave];
                s.x += r.x; s.y += r.y; s.z += r.z; s.w += r.w;
            }
            float4 o;
            o.x = tanhf(s.x + b4.x);
            o.y = tanhf(s.y + b4.y);
            o.z = tanhf(s.z + b4.z);
            o.w = tanhf(s.w + b4.w);
            // mirror own 32 columns into LDS for next step (skip reload)
            *(float4*)&ht[wave][(jblk << 5) + (lane << 2)] = o;
            // write-through + wave-lockstep drain, then publish
            sc_store4(out + ((size_t)t * BATCH + b0 + wave) * HDIM + jj, o);
            if (t == T_STEPS - 1)
                *(float4*)(hfin + (size_t)(b0 + wave) * HDIM + jj) = o;
        }
        if (lane == 0)
            flag_store(fl_base + jblk, (unsigned)(t + 1));
    }
}

extern "C" void kernel_launch(void* const* d_in, const int* in_sizes, int n_in,
                              void* d_out, int out_size, void* d_ws, size_t ws_size,
                              hipStream_t stream) {
    const float* x    = (const float*)d_in[0];
    const float* h0   = (const float*)d_in[1];
    const float* w_ih = (const float*)d_in[2];   // [1024][128]
    const float* w_hh = (const float*)d_in[3];   // [1024][1024]
    const float* bias = (const float*)d_in[4];   // [1024]
    float* out = (float*)d_out;

    char* ws = (char*)d_ws;
    float*    WT    = (float*)ws;                // [1152][1024] = 4.72 MB
    unsigned* flags = (unsigned*)(ws + 4718592); // 8*8*32 dwords = 8 KB

    (void)hipMemsetAsync(flags, 0, 8192, stream);
    transpose_f32<<<256, 256, 0, stream>>>(w_hh, WT, HDIM, HDIM);
    transpose_f32<<<32, 256, 0, stream>>>(w_ih, WT + (size_t)HDIM * HDIM, HDIM, IDIM);
    esn_persistent<<<NWG, 512, 0, stream>>>(x, h0, WT, bias,
                                            out, out + (size_t)T_STEPS * BATCH * HDIM,
                                            flags);
}

// Round 4
// 3379.998 us; speedup vs baseline: 1.0423x; 1.0423x over previous
//
#include <hip/hip_runtime.h>
#include <math.h>

// ESN: 512 sequential steps of h = tanh([h | x_t] @ [W_hh|W_ih]^T + b)
// T=512, B=64, I=128, H=1024, K' = 1152.
//
// R8 (from R7 @ 3.52 ms, R6 @ 3.13 ms): R7's decentralized per-row flag sync
// + R6's conflict-free staging pattern. R7's regression was 96.5M LDS bank
// conflicts (23x R6): lane-chunked 256B-stride ds_write_b128 put all 64
// lanes on one bank quad. Fix: poll the whole 32-producer flag line per row
// (one coalesced 128B load + __all ballot), then stage with R6's pattern
// (lane l: float4 at 16l + {0,1024,2048,3072} B -> 4 coalesced 1KB loads,
// LDS writes spread over 8 bank quads).
//  * Per-wave publish kept: each wave epilogues its row (lanes 0-7),
//    wave-lockstep vmcnt(0) drain, immediate flag store -- no WG barrier
//    between drain and publish. 2 syncthreads per step.
//  * W (18 float4) + bias in VGPRs all 512 steps; sc0/sc1 write-through data
//    stores (no buffer_wbl2); x_t prefetched one step ahead.

#define T_STEPS 512
#define BATCH   64
#define HDIM    1024
#define IDIM    128
#define KDIM    1152
#define NWG     256
#define NB      8

typedef float f32x4_t __attribute__((ext_vector_type(4)));

__device__ __forceinline__ unsigned sc_load(const unsigned* p) {
    unsigned v;
    asm volatile("global_load_dword %0, %1, off sc0 sc1\n\ts_waitcnt vmcnt(0)"
                 : "=&v"(v) : "v"(p) : "memory");
    return v;
}

// 4x16B bypass loads at 1KB stride off one address (13-bit signed imm ok),
// single drain.
__device__ __forceinline__ void sc_load4x4o(const float* p, float4& a, float4& b,
                                            float4& c, float4& d) {
    asm volatile(
        "global_load_dwordx4 %0, %4, off sc0 sc1\n\t"
        "global_load_dwordx4 %1, %4, off offset:1024 sc0 sc1\n\t"
        "global_load_dwordx4 %2, %4, off offset:2048 sc0 sc1\n\t"
        "global_load_dwordx4 %3, %4, off offset:3072 sc0 sc1\n\t"
        "s_waitcnt vmcnt(0)"
        : "=&v"(a), "=&v"(b), "=&v"(c), "=&v"(d)
        : "v"(p)
        : "memory");
}

// write-through store to the coherence point + drain (s_waitcnt is wave-wide:
// drains ALL lanes' outstanding stores).
__device__ __forceinline__ void sc_store4(float* p, float4 v) {
    f32x4_t t;
    t.x = v.x; t.y = v.y; t.z = v.z; t.w = v.w;
    asm volatile("global_store_dwordx4 %0, %1, off sc0 sc1\n\ts_waitcnt vmcnt(0)"
                 :: "v"(p), "v"(t) : "memory");
}

__device__ __forceinline__ void flag_store(unsigned* p, unsigned v) {
    asm volatile("global_store_dword %0, %1, off sc0 sc1"
                 :: "v"(p), "v"(v) : "memory");
}

// src[R][C] -> dst[C][R], 64x64 LDS tiles, grid = (C/64)*(R/64), 256 thr
__global__ void transpose_f32(const float* __restrict__ src, float* __restrict__ dst,
                              int R, int C) {
    __shared__ float tile[64][65];
    const int tcol = threadIdx.x & 63;
    const int trow = threadIdx.x >> 6;
    const int nbx = C >> 6;
    const int bx = blockIdx.x % nbx;
    const int by = blockIdx.x / nbx;
    const int c0 = bx << 6, r0 = by << 6;
    for (int i = trow; i < 64; i += 4)
        tile[i][tcol] = src[(size_t)(r0 + i) * C + c0 + tcol];
    __syncthreads();
    for (int i = trow; i < 64; i += 4)
        dst[(size_t)(c0 + i) * R + r0 + tcol] = tile[tcol][i];
}

__global__ __launch_bounds__(512) void esn_persistent(
    const float* __restrict__ x,     // [512][64][128]
    const float* __restrict__ h0,    // [64][1024]
    const float* __restrict__ WT,    // [1152][1024]
    const float* __restrict__ bias,  // [1024]
    float* __restrict__ out,         // [512][64][1024]
    float* __restrict__ hfin,        // [64][1024]
    unsigned* flags)                 // [8 bgrp][8 row][32 jblk] dwords
{
    const int tid  = threadIdx.x;
    const int wg   = blockIdx.x;
    const int wave = tid >> 6;                       // 0..7 = owned batch row
    const int lane = tid & 63;
    const int jq   = lane & 7;                       // 4 j each -> 32 j
    const int ksub = lane >> 3;                      // 0..7 k-interleave
    const int jblk = ((wg & 7) << 2) | ((wg >> 3) & 3);  // XCD owns 4 jblks
    const int bgrp = wg >> 5;                            // 0..7
    const int b0   = bgrp << 3;
    const int j0   = (jblk << 5) + (jq << 2);
    const int krec = wave << 7;                      // recurrent k base (128/wave)
    const int kx   = HDIM + (wave << 4) + (ksub << 1);  // x-part rows (2 each)

    __shared__ float  ht[NB][KDIM];                  // 36.9 KB row-major
    __shared__ float4 red[8 * 8 * 9];                // [w][jq] stride 9, +b pad

    // ---- hoist all 18 W float4 loads for ALL 512 steps (72 VGPRs) ----
    float4 Wv[18];
    {
        const float* wp = WT + (size_t)krec * HDIM + j0;
        #pragma unroll
        for (int i = 0; i < 4; ++i) {
            const int kk = ((i << 3) + ksub) << 2;      // 0..124 step 4
            const float* wk = wp + (size_t)kk * HDIM;
            Wv[i * 4 + 0] = *(const float4*)(wk);
            Wv[i * 4 + 1] = *(const float4*)(wk + HDIM);
            Wv[i * 4 + 2] = *(const float4*)(wk + 2 * HDIM);
            Wv[i * 4 + 3] = *(const float4*)(wk + 3 * HDIM);
        }
        const float* wkx = WT + (size_t)kx * HDIM + j0;
        Wv[16] = *(const float4*)(wkx);
        Wv[17] = *(const float4*)(wkx + HDIM);
    }

    // ---- epilogue constants: lanes 0-7 of EVERY wave handle row b0+wave ----
    float4 b4 = make_float4(0.f, 0.f, 0.f, 0.f);
    int jj = 0;
    if (lane < 8) {
        jj = (jblk << 5) + (lane << 2);
        b4 = *(const float4*)(bias + jj);
    }

    // per-row flag line: 32 contiguous dwords per (bgrp,row)
    unsigned* fl_base = flags + (((bgrp << 3) + wave) << 5);
    const unsigned* fl_poll = fl_base + (lane & 31);

    // ---- prefetch x row for t=0 (plain cached load, x is read-only) ----
    float4 xv = make_float4(0.f, 0.f, 0.f, 0.f);
    if (lane < 32)
        xv = *(const float4*)(x + (size_t)(b0 + wave) * IDIM + (lane << 2));

    for (int t = 0; t < T_STEPS; ++t) {
        // ---- stage [h_{t-1} | x_t] row (b0+wave) into LDS ----
        if (lane < 32)
            *(float4*)&ht[wave][HDIM + (lane << 2)] = xv;
        if (t == 0) {
            const float* p = h0 + (size_t)(b0 + wave) * HDIM + (lane << 2);
            *(float4*)&ht[wave][(lane << 2)]       = *(const float4*)(p);
            *(float4*)&ht[wave][256 + (lane << 2)] = *(const float4*)(p + 256);
            *(float4*)&ht[wave][512 + (lane << 2)] = *(const float4*)(p + 512);
            *(float4*)&ht[wave][768 + (lane << 2)] = *(const float4*)(p + 768);
        } else {
            // wait for all 32 producers of this row (coalesced 128B poll)
            unsigned f;
            do { f = sc_load(fl_poll); } while (!__all((int)(f >= (unsigned)t)));
            float4 a, b, c, d;
            sc_load4x4o(out + ((size_t)(t - 1) * BATCH + b0 + wave) * HDIM
                        + (lane << 2), a, b, c, d);
            *(float4*)&ht[wave][(lane << 2)]       = a;
            *(float4*)&ht[wave][256 + (lane << 2)] = b;
            *(float4*)&ht[wave][512 + (lane << 2)] = c;
            *(float4*)&ht[wave][768 + (lane << 2)] = d;
        }
        __syncthreads();                               // ht complete

        // prefetch next x row; latency hides under the FMA phase
        if (t + 1 < T_STEPS && lane < 32)
            xv = *(const float4*)(x + ((size_t)(t + 1) * BATCH + b0 + wave) * IDIM
                                  + (lane << 2));

        // ---- FMA: acc[b] over this thread's k (W in registers) ----
        float4 acc[NB];
        #pragma unroll
        for (int bb = 0; bb < NB; ++bb) acc[bb] = make_float4(0.f, 0.f, 0.f, 0.f);

        #pragma unroll
        for (int i = 0; i < 4; ++i) {
            const int kk = krec + ((((i << 3) + ksub)) << 2);
            const float4 w0 = Wv[i * 4 + 0], w1 = Wv[i * 4 + 1];
            const float4 w2 = Wv[i * 4 + 2], w3 = Wv[i * 4 + 3];
            #pragma unroll
            for (int bb = 0; bb < NB; ++bb) {
                float4 h4 = *(const float4*)&ht[bb][kk];
                acc[bb].x = fmaf(w0.x, h4.x, acc[bb].x);
                acc[bb].y = fmaf(w0.y, h4.x, acc[bb].y);
                acc[bb].z = fmaf(w0.z, h4.x, acc[bb].z);
                acc[bb].w = fmaf(w0.w, h4.x, acc[bb].w);
                acc[bb].x = fmaf(w1.x, h4.y, acc[bb].x);
                acc[bb].y = fmaf(w1.y, h4.y, acc[bb].y);
                acc[bb].z = fmaf(w1.z, h4.y, acc[bb].z);
                acc[bb].w = fmaf(w1.w, h4.y, acc[bb].w);
                acc[bb].x = fmaf(w2.x, h4.z, acc[bb].x);
                acc[bb].y = fmaf(w2.y, h4.z, acc[bb].y);
                acc[bb].z = fmaf(w2.z, h4.z, acc[bb].z);
                acc[bb].w = fmaf(w2.w, h4.z, acc[bb].w);
                acc[bb].x = fmaf(w3.x, h4.w, acc[bb].x);
                acc[bb].y = fmaf(w3.y, h4.w, acc[bb].y);
                acc[bb].z = fmaf(w3.z, h4.w, acc[bb].z);
                acc[bb].w = fmaf(w3.w, h4.w, acc[bb].w);
            }
        }
        // x tail: 2 k per thread
        #pragma unroll
        for (int bb = 0; bb < NB; ++bb) {
            float2 hx = *(const float2*)&ht[bb][kx];
            acc[bb].x = fmaf(Wv[16].x, hx.x, acc[bb].x);
            acc[bb].y = fmaf(Wv[16].y, hx.x, acc[bb].y);
            acc[bb].z = fmaf(Wv[16].z, hx.x, acc[bb].z);
            acc[bb].w = fmaf(Wv[16].w, hx.x, acc[bb].w);
            acc[bb].x = fmaf(Wv[17].x, hx.y, acc[bb].x);
            acc[bb].y = fmaf(Wv[17].y, hx.y, acc[bb].y);
            acc[bb].z = fmaf(Wv[17].z, hx.y, acc[bb].z);
            acc[bb].w = fmaf(Wv[17].w, hx.y, acc[bb].w);
        }

        // ---- reduce over ksub (lane bits 3,4,5) ----
        #pragma unroll
        for (int bb = 0; bb < NB; ++bb) {
            acc[bb].x += __shfl_xor(acc[bb].x, 8);
            acc[bb].y += __shfl_xor(acc[bb].y, 8);
            acc[bb].z += __shfl_xor(acc[bb].z, 8);
            acc[bb].w += __shfl_xor(acc[bb].w, 8);
            acc[bb].x += __shfl_xor(acc[bb].x, 16);
            acc[bb].y += __shfl_xor(acc[bb].y, 16);
            acc[bb].z += __shfl_xor(acc[bb].z, 16);
            acc[bb].w += __shfl_xor(acc[bb].w, 16);
            acc[bb].x += __shfl_xor(acc[bb].x, 32);
            acc[bb].y += __shfl_xor(acc[bb].y, 32);
            acc[bb].z += __shfl_xor(acc[bb].z, 32);
            acc[bb].w += __shfl_xor(acc[bb].w, 32);
        }
        if (ksub == 0) {
            #pragma unroll
            for (int bb = 0; bb < NB; ++bb)
                red[((wave << 3) + jq) * 9 + bb] = acc[bb];
        }
        __syncthreads();                               // red complete

        // ---- per-wave epilogue for row b0+wave: lanes 0-7 ----
        if (lane < 8) {
            float4 s = make_float4(0.f, 0.f, 0.f, 0.f);
            #pragma unroll
            for (int w = 0; w < 8; ++w) {
                float4 r = red[((w << 3) + lane) * 9 + wave];
                s.x += r.x; s.y += r.y; s.z += r.z; s.w += r.w;
            }
            float4 o;
            o.x = tanhf(s.x + b4.x);
            o.y = tanhf(s.y + b4.y);
            o.z = tanhf(s.z + b4.z);
            o.w = tanhf(s.w + b4.w);
            // write-through + wave-lockstep drain, then publish
            sc_store4(out + ((size_t)t * BATCH + b0 + wave) * HDIM + jj, o);
            if (t == T_STEPS - 1)
                *(float4*)(hfin + (size_t)(b0 + wave) * HDIM + jj) = o;
        }
        if (lane == 0)
            flag_store(fl_base + jblk, (unsigned)(t + 1));
    }
}

extern "C" void kernel_launch(void* const* d_in, const int* in_sizes, int n_in,
                              void* d_out, int out_size, void* d_ws, size_t ws_size,
                              hipStream_t stream) {
    const float* x    = (const float*)d_in[0];
    const float* h0   = (const float*)d_in[1];
    const float* w_ih = (const float*)d_in[2];   // [1024][128]
    const float* w_hh = (const float*)d_in[3];   // [1024][1024]
    const float* bias = (const float*)d_in[4];   // [1024]
    float* out = (float*)d_out;

    char* ws = (char*)d_ws;
    float*    WT    = (float*)ws;                // [1152][1024] = 4.72 MB
    unsigned* flags = (unsigned*)(ws + 4718592); // 8*8*32 dwords = 8 KB

    (void)hipMemsetAsync(flags, 0, 8192, stream);
    transpose_f32<<<256, 256, 0, stream>>>(w_hh, WT, HDIM, HDIM);
    transpose_f32<<<32, 256, 0, stream>>>(w_ih, WT + (size_t)HDIM * HDIM, HDIM, IDIM);
    esn_persistent<<<NWG, 512, 0, stream>>>(x, h0, WT, bias,
                                            out, out + (size_t)T_STEPS * BATCH * HDIM,
                                            flags);
}

// Round 5
// 3114.991 us; speedup vs baseline: 1.1309x; 1.0851x over previous
//
#include <hip/hip_runtime.h>
#include <math.h>

// ESN: 512 sequential steps of h = tanh([h | x_t] @ [W_hh|W_ih]^T + b)
// T=512, B=64, I=128, H=1024, K' = 1152.
//
// R9 (from R8 @ 3.38 ms, R6 @ 3.13 ms): per-wave k-slice staging.
//  * Wave w of WG (bgrp,jblk) consumes ONLY k in [128w,128w+128) (+x cols
//    [16w,16w+16)) of its 8 rows -- produced by exactly 4 WGs (jblk 4w..4w+3).
//    So wave w polls its own 32 flags ([bgrp][jblk][row] layout -> one
//    coalesced 128B line), stages its 4KB slice into a WAVE-PRIVATE LDS
//    block, and starts FMA immediately: NO pre-FMA __syncthreads.
//  * ONE __syncthreads per step (before cross-wave red reduce); red[] is
//    parity double-buffered so waves may slip a full step without racing.
//  * Staging lane map: global = 2 rows x 512B contiguous per instruction
//    (coalesced); LDS = contiguous 1KB wave-chunks (0-conflict, R8-proven).
//    FMA read pattern unchanged (conflict-free).
//  * Kept: W (18 float4) + bias in VGPRs all 512 steps, sc0/sc1 bypass
//    loads / write-through stores (no cache maintenance), per-wave publish
//    after wave-lockstep drain, x_t prefetch (now float2/lane).

#define T_STEPS 512
#define BATCH   64
#define HDIM    1024
#define IDIM    128
#define KDIM    1152
#define NWG     256
#define NB      8

typedef float f32x4_t __attribute__((ext_vector_type(4)));

__device__ __forceinline__ unsigned sc_load(const unsigned* p) {
    unsigned v;
    asm volatile("global_load_dword %0, %1, off sc0 sc1\n\ts_waitcnt vmcnt(0)"
                 : "=&v"(v) : "v"(p) : "memory");
    return v;
}

// 4 x 16B bypass loads from 4 addresses, single drain.
__device__ __forceinline__ void sc_load4x4(const float* p0, const float* p1,
                                           const float* p2, const float* p3,
                                           float4& a, float4& b,
                                           float4& c, float4& d) {
    asm volatile(
        "global_load_dwordx4 %0, %4, off sc0 sc1\n\t"
        "global_load_dwordx4 %1, %5, off sc0 sc1\n\t"
        "global_load_dwordx4 %2, %6, off sc0 sc1\n\t"
        "global_load_dwordx4 %3, %7, off sc0 sc1\n\t"
        "s_waitcnt vmcnt(0)"
        : "=&v"(a), "=&v"(b), "=&v"(c), "=&v"(d)
        : "v"(p0), "v"(p1), "v"(p2), "v"(p3)
        : "memory");
}

// write-through store to the coherence point + drain (s_waitcnt is wave-wide).
__device__ __forceinline__ void sc_store4(float* p, float4 v) {
    f32x4_t t;
    t.x = v.x; t.y = v.y; t.z = v.z; t.w = v.w;
    asm volatile("global_store_dwordx4 %0, %1, off sc0 sc1\n\ts_waitcnt vmcnt(0)"
                 :: "v"(p), "v"(t) : "memory");
}

__device__ __forceinline__ void flag_store(unsigned* p, unsigned v) {
    asm volatile("global_store_dword %0, %1, off sc0 sc1"
                 :: "v"(p), "v"(v) : "memory");
}

// src[R][C] -> dst[C][R], 64x64 LDS tiles, grid = (C/64)*(R/64), 256 thr
__global__ void transpose_f32(const float* __restrict__ src, float* __restrict__ dst,
                              int R, int C) {
    __shared__ float tile[64][65];
    const int tcol = threadIdx.x & 63;
    const int trow = threadIdx.x >> 6;
    const int nbx = C >> 6;
    const int bx = blockIdx.x % nbx;
    const int by = blockIdx.x / nbx;
    const int c0 = bx << 6, r0 = by << 6;
    for (int i = trow; i < 64; i += 4)
        tile[i][tcol] = src[(size_t)(r0 + i) * C + c0 + tcol];
    __syncthreads();
    for (int i = trow; i < 64; i += 4)
        dst[(size_t)(c0 + i) * R + r0 + tcol] = tile[tcol][i];
}

__global__ __launch_bounds__(512) void esn_persistent(
    const float* __restrict__ x,     // [512][64][128]
    const float* __restrict__ h0,    // [64][1024]
    const float* __restrict__ WT,    // [1152][1024]
    const float* __restrict__ bias,  // [1024]
    float* __restrict__ out,         // [512][64][1024]
    float* __restrict__ hfin,        // [64][1024]
    unsigned* flags)                 // [8 bgrp][32 jblk][8 row] dwords
{
    const int tid  = threadIdx.x;
    const int wg   = blockIdx.x;
    const int wave = tid >> 6;                       // 0..7 (k-slice / epi row)
    const int lane = tid & 63;
    const int jq   = lane & 7;                       // 4 j each -> 32 j
    const int ksub = lane >> 3;                      // 0..7 k-interleave
    const int jblk = ((wg & 7) << 2) | ((wg >> 3) & 3);  // XCD owns 4 jblks
    const int bgrp = wg >> 5;                            // 0..7
    const int b0   = bgrp << 3;
    const int j0   = (jblk << 5) + (jq << 2);
    const int krec = wave << 7;                      // recurrent k base (128/wave)
    const int kx   = HDIM + (wave << 4) + (ksub << 1);  // x-part rows (2 each)

    // wave-private staging blocks
    __shared__ float  ht2[8 * 1024];                 // [wave][8 rows][128 k] 32KB
    __shared__ float  htx[8 * 128];                  // [wave][8 rows][16 xk]  4KB
    __shared__ float4 red[2][8 * 8 * 9];             // parity-dbuf reduce    18KB

    // ---- hoist all 18 W float4 loads for ALL 512 steps (72 VGPRs) ----
    float4 Wv[18];
    {
        const float* wp = WT + (size_t)krec * HDIM + j0;
        #pragma unroll
        for (int i = 0; i < 4; ++i) {
            const int kk = ((i << 3) + ksub) << 2;      // 0..124 step 4
            const float* wk = wp + (size_t)kk * HDIM;
            Wv[i * 4 + 0] = *(const float4*)(wk);
            Wv[i * 4 + 1] = *(const float4*)(wk + HDIM);
            Wv[i * 4 + 2] = *(const float4*)(wk + 2 * HDIM);
            Wv[i * 4 + 3] = *(const float4*)(wk + 3 * HDIM);
        }
        const float* wkx = WT + (size_t)kx * HDIM + j0;
        Wv[16] = *(const float4*)(wkx);
        Wv[17] = *(const float4*)(wkx + HDIM);
    }

    // ---- epilogue constants: lanes 0-7 of wave v handle row b0+v ----
    float4 b4 = make_float4(0.f, 0.f, 0.f, 0.f);
    int jj = 0;
    if (lane < 8) {
        jj = (jblk << 5) + (lane << 2);
        b4 = *(const float4*)(bias + jj);
    }

    // ---- flag layout: fl[(bgrp<<8) + (jblk<<3) + row] ----
    unsigned* fl_pub = flags + (bgrp << 8) + (jblk << 3) + wave;
    const unsigned* fl_poll = flags + (bgrp << 8) + (wave << 5) + (lane & 31);

    // ---- staging lane maps ----
    const int sbb = lane >> 5;                 // row parity (0/1)
    const int sko = (lane & 31) << 2;          // k-offset within slice
    float* hdst = ht2 + (wave << 10) + (lane << 2);      // contiguous 1KB/instr
    const int xr = lane >> 3;                  // x row
    const int xco = (lane & 7) << 1;           // x col-offset within slice
    float* xdst = htx + (wave << 7) + (xr << 4) + xco;
    const float* hb = ht2 + (wave << 10);
    const float* xb = htx + (wave << 7);

    // ---- prefetch x slice for t=0 (plain cached load, x read-only) ----
    float2 xv2 = *(const float2*)(x + (size_t)(b0 + xr) * IDIM + (wave << 4) + xco);

    for (int t = 0; t < T_STEPS; ++t) {
        // ---- stage this wave's k-slice of 8 rows into wave-private LDS ----
        *(float2*)xdst = xv2;
        if (t == 0) {
            const float* p = h0 + (size_t)(b0 + sbb) * HDIM + krec + sko;
            *(float4*)(hdst)       = *(const float4*)(p);
            *(float4*)(hdst + 256) = *(const float4*)(p + 2 * HDIM);
            *(float4*)(hdst + 512) = *(const float4*)(p + 4 * HDIM);
            *(float4*)(hdst + 768) = *(const float4*)(p + 6 * HDIM);
        } else {
            // wait for THIS wave's 32 producers (4 jblk x 8 rows, coalesced)
            unsigned f;
            do { f = sc_load(fl_poll); } while (!__all((int)(f >= (unsigned)t)));
            const float* p = out + ((size_t)(t - 1) * BATCH + b0 + sbb) * HDIM
                             + krec + sko;
            float4 a, b, c, d;
            sc_load4x4(p, p + 2 * HDIM, p + 4 * HDIM, p + 6 * HDIM, a, b, c, d);
            *(float4*)(hdst)       = a;
            *(float4*)(hdst + 256) = b;
            *(float4*)(hdst + 512) = c;
            *(float4*)(hdst + 768) = d;
        }
        // NO __syncthreads: staged data is wave-private (written & read by
        // this wave only); compiler inserts the lgkmcnt wait.

        // prefetch next x slice; latency hides under the FMA phase
        if (t + 1 < T_STEPS)
            xv2 = *(const float2*)(x + ((size_t)(t + 1) * BATCH + b0 + xr) * IDIM
                                   + (wave << 4) + xco);

        // ---- FMA: acc[b] over this thread's k (W in registers) ----
        float4 acc[NB];
        #pragma unroll
        for (int bb = 0; bb < NB; ++bb) acc[bb] = make_float4(0.f, 0.f, 0.f, 0.f);

        #pragma unroll
        for (int i = 0; i < 4; ++i) {
            const int ko = ((i << 3) + ksub) << 2;       // 0..124 step 4
            const float4 w0 = Wv[i * 4 + 0], w1 = Wv[i * 4 + 1];
            const float4 w2 = Wv[i * 4 + 2], w3 = Wv[i * 4 + 3];
            #pragma unroll
            for (int bb = 0; bb < NB; ++bb) {
                float4 h4 = *(const float4*)(hb + (bb << 7) + ko);
                acc[bb].x = fmaf(w0.x, h4.x, acc[bb].x);
                acc[bb].y = fmaf(w0.y, h4.x, acc[bb].y);
                acc[bb].z = fmaf(w0.z, h4.x, acc[bb].z);
                acc[bb].w = fmaf(w0.w, h4.x, acc[bb].w);
                acc[bb].x = fmaf(w1.x, h4.y, acc[bb].x);
                acc[bb].y = fmaf(w1.y, h4.y, acc[bb].y);
                acc[bb].z = fmaf(w1.z, h4.y, acc[bb].z);
                acc[bb].w = fmaf(w1.w, h4.y, acc[bb].w);
                acc[bb].x = fmaf(w2.x, h4.z, acc[bb].x);
                acc[bb].y = fmaf(w2.y, h4.z, acc[bb].y);
                acc[bb].z = fmaf(w2.z, h4.z, acc[bb].z);
                acc[bb].w = fmaf(w2.w, h4.z, acc[bb].w);
                acc[bb].x = fmaf(w3.x, h4.w, acc[bb].x);
                acc[bb].y = fmaf(w3.y, h4.w, acc[bb].y);
                acc[bb].z = fmaf(w3.z, h4.w, acc[bb].z);
                acc[bb].w = fmaf(w3.w, h4.w, acc[bb].w);
            }
        }
        // x tail: 2 k per thread
        #pragma unroll
        for (int bb = 0; bb < NB; ++bb) {
            float2 hx = *(const float2*)(xb + (bb << 4) + (ksub << 1));
            acc[bb].x = fmaf(Wv[16].x, hx.x, acc[bb].x);
            acc[bb].y = fmaf(Wv[16].y, hx.x, acc[bb].y);
            acc[bb].z = fmaf(Wv[16].z, hx.x, acc[bb].z);
            acc[bb].w = fmaf(Wv[16].w, hx.x, acc[bb].w);
            acc[bb].x = fmaf(Wv[17].x, hx.y, acc[bb].x);
            acc[bb].y = fmaf(Wv[17].y, hx.y, acc[bb].y);
            acc[bb].z = fmaf(Wv[17].z, hx.y, acc[bb].z);
            acc[bb].w = fmaf(Wv[17].w, hx.y, acc[bb].w);
        }

        // ---- reduce over ksub (lane bits 3,4,5) ----
        #pragma unroll
        for (int bb = 0; bb < NB; ++bb) {
            acc[bb].x += __shfl_xor(acc[bb].x, 8);
            acc[bb].y += __shfl_xor(acc[bb].y, 8);
            acc[bb].z += __shfl_xor(acc[bb].z, 8);
            acc[bb].w += __shfl_xor(acc[bb].w, 8);
            acc[bb].x += __shfl_xor(acc[bb].x, 16);
            acc[bb].y += __shfl_xor(acc[bb].y, 16);
            acc[bb].z += __shfl_xor(acc[bb].z, 16);
            acc[bb].w += __shfl_xor(acc[bb].w, 16);
            acc[bb].x += __shfl_xor(acc[bb].x, 32);
            acc[bb].y += __shfl_xor(acc[bb].y, 32);
            acc[bb].z += __shfl_xor(acc[bb].z, 32);
            acc[bb].w += __shfl_xor(acc[bb].w, 32);
        }
        if (ksub == 0) {
            #pragma unroll
            for (int bb = 0; bb < NB; ++bb)
                red[t & 1][((wave << 3) + jq) * 9 + bb] = acc[bb];
        }
        __syncthreads();                               // red[t&1] complete

        // ---- per-wave epilogue for row b0+wave: lanes 0-7 ----
        if (lane < 8) {
            float4 s = make_float4(0.f, 0.f, 0.f, 0.f);
            #pragma unroll
            for (int w = 0; w < 8; ++w) {
                float4 r = red[t & 1][((w << 3) + lane) * 9 + wave];
                s.x += r.x; s.y += r.y; s.z += r.z; s.w += r.w;
            }
            float4 o;
            o.x = tanhf(s.x + b4.x);
            o.y = tanhf(s.y + b4.y);
            o.z = tanhf(s.z + b4.z);
            o.w = tanhf(s.w + b4.w);
            // write-through + wave-lockstep drain, then publish
            sc_store4(out + ((size_t)t * BATCH + b0 + wave) * HDIM + jj, o);
            if (t == T_STEPS - 1)
                *(float4*)(hfin + (size_t)(b0 + wave) * HDIM + jj) = o;
        }
        if (lane == 0)
            flag_store(fl_pub, (unsigned)(t + 1));
    }
}

extern "C" void kernel_launch(void* const* d_in, const int* in_sizes, int n_in,
                              void* d_out, int out_size, void* d_ws, size_t ws_size,
                              hipStream_t stream) {
    const float* x    = (const float*)d_in[0];
    const float* h0   = (const float*)d_in[1];
    const float* w_ih = (const float*)d_in[2];   // [1024][128]
    const float* w_hh = (const float*)d_in[3];   // [1024][1024]
    const float* bias = (const float*)d_in[4];   // [1024]
    float* out = (float*)d_out;

    char* ws = (char*)d_ws;
    float*    WT    = (float*)ws;                // [1152][1024] = 4.72 MB
    unsigned* flags = (unsigned*)(ws + 4718592); // 8*32*8 dwords = 8 KB

    (void)hipMemsetAsync(flags, 0, 8192, stream);
    transpose_f32<<<256, 256, 0, stream>>>(w_hh, WT, HDIM, HDIM);
    transpose_f32<<<32, 256, 0, stream>>>(w_ih, WT + (size_t)HDIM * HDIM, HDIM, IDIM);
    esn_persistent<<<NWG, 512, 0, stream>>>(x, h0, WT, bias,
                                            out, out + (size_t)T_STEPS * BATCH * HDIM,
                                            flags);
}